// Round 2
// baseline (864.066 us; speedup 1.0000x reference)
//
#include <hip/hip_runtime.h>
#include <math.h>

#define D 64

__global__ void k_zero(int* __restrict__ a, int n) {
  int i = blockIdx.x * blockDim.x + threadIdx.x;
  if (i < n) a[i] = 0;
}

__global__ void k_hist(const int* __restrict__ row, int* __restrict__ cnt, int E) {
  int e = blockIdx.x * blockDim.x + threadIdx.x;
  if (e < E) atomicAdd(&cnt[row[e]], 1);
}

// single-block exclusive scan over cnt[0..N) -> rowptr[0..N]
__global__ void k_scan(const int* __restrict__ cnt, int* __restrict__ rowptr, int N) {
  __shared__ int sums[256];
  int t = threadIdx.x;
  int chunk = (N + 255) >> 8;
  int lo = t * chunk;
  int hi = lo + chunk; if (hi > N) hi = N; if (lo > N) lo = N;
  int s = 0;
  for (int i = lo; i < hi; ++i) s += cnt[i];
  sums[t] = s;
  __syncthreads();
  for (int off = 1; off < 256; off <<= 1) {
    int v = (t >= off) ? sums[t - off] : 0;
    __syncthreads();
    sums[t] += v;
    __syncthreads();
  }
  int run = (t == 0) ? 0 : sums[t - 1];
  for (int i = lo; i < hi; ++i) { rowptr[i] = run; run += cnt[i]; }
  if (t == 255) rowptr[N] = run;  // == E
}

__global__ void k_scatter(const int* __restrict__ row, const int* __restrict__ col,
                          const float* __restrict__ val, const int* __restrict__ rowptr,
                          int* __restrict__ fill, int* __restrict__ ccol,
                          float* __restrict__ cval, int E) {
  int e = blockIdx.x * blockDim.x + threadIdx.x;
  if (e < E) {
    int r = row[e];
    int pos = rowptr[r] + atomicAdd(&fill[r], 1);
    ccol[pos] = col[e];
    cval[pos] = val[e];
  }
}

__global__ void k_init_emb(const float4* __restrict__ ut, const float4* __restrict__ it,
                           float4* __restrict__ emb, int nu4, int tot4) {
  int i = blockIdx.x * blockDim.x + threadIdx.x;
  if (i < tot4) emb[i] = (i < nu4) ? ut[i] : it[i - nu4];
}

// one wave per row, one lane per d; fully coalesced 256B row gathers, no atomics
__global__ void k_prop(const float* __restrict__ ein, float* __restrict__ eout,
                       const int* __restrict__ rowptr, const int* __restrict__ ccol,
                       const float* __restrict__ cval, int N) {
  int w = (blockIdx.x * blockDim.x + threadIdx.x) >> 6;
  int lane = threadIdx.x & 63;
  if (w >= N) return;
  int beg = rowptr[w], end = rowptr[w + 1];
  float acc = 0.f;
  for (int k = beg; k < end; ++k) {
    int c = ccol[k];
    float v = cval[k];
    acc = fmaf(v, ein[(size_t)c * D + lane], acc);
  }
  eout[(size_t)w * D + lane] = acc;
}

__global__ void k_gather(const float* __restrict__ emb, const int* __restrict__ users,
                         const int* __restrict__ items, float* __restrict__ uacc,
                         float* __restrict__ iacc, int B, int NU, int store) {
  int i = blockIdx.x * blockDim.x + threadIdx.x;
  if (i >= B * D) return;
  int b = i >> 6, d = i & 63;
  float uv = emb[(size_t)users[b] * D + d];
  float iv = emb[(size_t)(NU + items[b]) * D + d];
  if (store) { uacc[i] = uv; iacc[i] = iv; }
  else       { uacc[i] += uv; iacc[i] += iv; }
}

// one wave per (user,item,xij) triple; 72-wide sigmoid/softmax dot
__global__ void k_final(const float* __restrict__ uacc, const float* __restrict__ iacc,
                        const float* __restrict__ xij, const float* __restrict__ xtab,
                        float* __restrict__ out, int B) {
  int w = (blockIdx.x * blockDim.x + threadIdx.x) >> 6;
  int lane = threadIdx.x & 63;
  if (w >= B) return;
  float ue = uacc[w * D + lane] * 0.25f;   // /(L+1)
  float ie = iacc[w * D + lane] * 0.25f;
  float xs = xij[w] - 0.3f;
  float xe = (lane < 8) ? xtab[lane] * xs : 0.f;

  // softmax over 72 values: 64 lane values + 8 extras on lanes 0..7
  float m = (lane < 8) ? fmaxf(ie, xe) : ie;
  for (int off = 32; off; off >>= 1) m = fmaxf(m, __shfl_xor(m, off));
  float e1 = expf(ie - m);
  float e2 = (lane < 8) ? expf(xe - m) : 0.f;
  float s = e1 + e2;
  for (int off = 32; off; off >>= 1) s += __shfl_xor(s, off);
  float inv = 1.f / s;

  float sig1 = 1.f / (1.f + expf(-ue));
  float term = sig1 * e1 * inv;
  if (lane < 8) {
    float sig2 = 1.f / (1.f + expf(-xe));
    term += sig2 * e2 * inv;
  }
  for (int off = 32; off; off >>= 1) term += __shfl_xor(term, off);
  if (lane == 0) out[w] = term;
}

extern "C" void kernel_launch(void* const* d_in, const int* in_sizes, int n_in,
                              void* d_out, int out_size, void* d_ws, size_t ws_size,
                              hipStream_t stream) {
  const int*   users = (const int*)d_in[0];
  const int*   items = (const int*)d_in[1];
  const float* xij   = (const float*)d_in[2];
  const float* utab  = (const float*)d_in[3];
  const float* itab  = (const float*)d_in[4];
  const float* xtab  = (const float*)d_in[5];
  const int*   erow  = (const int*)d_in[6];
  const int*   ecol  = (const int*)d_in[7];
  const float* evalp = (const float*)d_in[8];
  float* out = (float*)d_out;

  int B  = in_sizes[0];
  int NU = in_sizes[3] / D;
  int NI = in_sizes[4] / D;
  int N  = NU + NI;
  int E  = in_sizes[6];

  char* ws = (char*)d_ws;
  size_t off = 0;
  auto carve = [&](size_t bytes) {
    void* p = ws + off;
    off += (bytes + 255) & ~(size_t)255;
    return p;
  };
  float* embA   = (float*)carve((size_t)N * D * 4);
  float* embB   = (float*)carve((size_t)N * D * 4);
  int*   rowptr = (int*)carve((size_t)(N + 1) * 4);
  int*   cnt    = (int*)carve((size_t)N * 4);
  int*   fill   = (int*)carve((size_t)N * 4);
  int*   ccol   = (int*)carve((size_t)E * 4);
  float* cval   = (float*)carve((size_t)E * 4);
  float* uacc   = (float*)carve((size_t)B * D * 4);
  float* iacc   = (float*)carve((size_t)B * D * 4);
  (void)ws_size; (void)n_in; (void)out_size;

  // --- CSR build (every call; ws is re-poisoned by harness) ---
  hipLaunchKernelGGL(k_zero, dim3((N + 255) / 256), dim3(256), 0, stream, cnt, N);
  hipLaunchKernelGGL(k_zero, dim3((N + 255) / 256), dim3(256), 0, stream, fill, N);
  hipLaunchKernelGGL(k_hist, dim3((E + 255) / 256), dim3(256), 0, stream, erow, cnt, E);
  hipLaunchKernelGGL(k_scan, dim3(1), dim3(256), 0, stream, cnt, rowptr, N);
  hipLaunchKernelGGL(k_scatter, dim3((E + 255) / 256), dim3(256), 0, stream,
                     erow, ecol, evalp, rowptr, fill, ccol, cval, E);

  // --- emb0 = concat(user_table, item_table) ---
  int tot4 = N * D / 4, nu4 = NU * D / 4;
  hipLaunchKernelGGL(k_init_emb, dim3((tot4 + 255) / 256), dim3(256), 0, stream,
                     (const float4*)utab, (const float4*)itab, (float4*)embA, nu4, tot4);

  // hop-0 gather (store), then 3 propagate+gather-add hops
  int gthreads = B * D;
  hipLaunchKernelGGL(k_gather, dim3((gthreads + 255) / 256), dim3(256), 0, stream,
                     embA, users, items, uacc, iacc, B, NU, 1);

  float* ein = embA; float* eout = embB;
  for (int l = 0; l < 3; ++l) {
    hipLaunchKernelGGL(k_prop, dim3((N * 64 + 255) / 256), dim3(256), 0, stream,
                       ein, eout, rowptr, ccol, cval, N);
    hipLaunchKernelGGL(k_gather, dim3((gthreads + 255) / 256), dim3(256), 0, stream,
                       eout, users, items, uacc, iacc, B, NU, 0);
    float* t = ein; ein = eout; eout = t;
  }

  hipLaunchKernelGGL(k_final, dim3((B * 64 + 255) / 256), dim3(256), 0, stream,
                     uacc, iacc, xij, xtab, out, B);
}

// Round 3
// 438.265 us; speedup vs baseline: 1.9716x; 1.9716x over previous
//
#include <hip/hip_runtime.h>
#include <math.h>

#define D 64

__global__ void k_zero(int* __restrict__ a, int n) {
  int i = blockIdx.x * blockDim.x + threadIdx.x;
  if (i < n) a[i] = 0;
}

__global__ void k_hist(const int* __restrict__ row, int* __restrict__ cnt, int E) {
  int e = blockIdx.x * blockDim.x + threadIdx.x;
  if (e < E) atomicAdd(&cnt[row[e]], 1);
}

// ---- parallel exclusive scan: cnt[0..N) -> rowptr[0..N] ----
// scan1: per-block (1024 elems) exclusive prefix into rowptr + block sum
__global__ void k_scan1(const int* __restrict__ cnt, int* __restrict__ rowptr,
                        int* __restrict__ bsum, int N) {
  __shared__ int sh[256];
  int t = threadIdx.x;
  int base = blockIdx.x * 1024 + t * 4;
  int v0 = 0, v1 = 0, v2 = 0, v3 = 0;
  if (base + 3 < N) {
    int4 q = *(const int4*)&cnt[base];
    v0 = q.x; v1 = q.y; v2 = q.z; v3 = q.w;
  } else {
    if (base + 0 < N) v0 = cnt[base + 0];
    if (base + 1 < N) v1 = cnt[base + 1];
    if (base + 2 < N) v2 = cnt[base + 2];
    if (base + 3 < N) v3 = cnt[base + 3];
  }
  int s = v0 + v1 + v2 + v3;
  sh[t] = s;
  __syncthreads();
  for (int off = 1; off < 256; off <<= 1) {
    int x = (t >= off) ? sh[t - off] : 0;
    __syncthreads();
    sh[t] += x;
    __syncthreads();
  }
  int excl = sh[t] - s;
  if (t == 255) bsum[blockIdx.x] = sh[255];
  int p0 = excl, p1 = p0 + v0, p2 = p1 + v1, p3 = p2 + v2;
  if (base + 3 < N) {
    *(int4*)&rowptr[base] = make_int4(p0, p1, p2, p3);
  } else {
    if (base + 0 < N) rowptr[base + 0] = p0;
    if (base + 1 < N) rowptr[base + 1] = p1;
    if (base + 2 < N) rowptr[base + 2] = p2;
    if (base + 3 < N) rowptr[base + 3] = p3;
  }
}

// scan2: single-block in-place exclusive scan of bsum[0..nb)
__global__ void k_scan2(int* __restrict__ a, int nb) {
  __shared__ int sums[256];
  int t = threadIdx.x;
  int chunk = (nb + 255) >> 8;
  int lo = t * chunk; if (lo > nb) lo = nb;
  int hi = lo + chunk; if (hi > nb) hi = nb;
  int s = 0;
  for (int i = lo; i < hi; ++i) s += a[i];
  sums[t] = s;
  __syncthreads();
  for (int off = 1; off < 256; off <<= 1) {
    int v = (t >= off) ? sums[t - off] : 0;
    __syncthreads();
    sums[t] += v;
    __syncthreads();
  }
  int run = (t == 0) ? 0 : sums[t - 1];
  for (int i = lo; i < hi; ++i) { int v = a[i]; a[i] = run; run += v; }
}

// scan3: add block offsets; set rowptr[N] = E
__global__ void k_scan3(int* __restrict__ rowptr, const int* __restrict__ boff,
                        int N, int E) {
  int i = blockIdx.x * blockDim.x + threadIdx.x;
  if (i < N) rowptr[i] += boff[i >> 10];
  if (i == 0) rowptr[N] = E;
}

// scatter edges into CSR slots; claims slots by counting cnt back down
__global__ void k_scatter(const int* __restrict__ row, const int* __restrict__ col,
                          const float* __restrict__ val, const int* __restrict__ rowptr,
                          int* __restrict__ cnt, float2* __restrict__ cpack, int E) {
  int e = blockIdx.x * blockDim.x + threadIdx.x;
  if (e < E) {
    int r = row[e];
    int slot = atomicSub(&cnt[r], 1) - 1;
    int pos = rowptr[r] + slot;
    cpack[pos] = make_float2(__int_as_float(col[e]), val[e]);
  }
}

__global__ void k_init_emb(const float4* __restrict__ ut, const float4* __restrict__ it,
                           float4* __restrict__ emb, int nu4, int tot4) {
  int i = blockIdx.x * blockDim.x + threadIdx.x;
  if (i < tot4) emb[i] = (i < nu4) ? ut[i] : it[i - nu4];
}

// one wave per row; lanes = 4 edge-slots x 16 float4-lanes; no atomics
__global__ void k_prop(const float4* __restrict__ ein, float4* __restrict__ eout,
                       const int* __restrict__ rowptr, const float2* __restrict__ cpack,
                       int N) {
  int w = (blockIdx.x * blockDim.x + threadIdx.x) >> 6;
  int lane = threadIdx.x & 63;
  if (w >= N) return;
  int sub = lane >> 4;      // edge slot 0..3
  int d4  = lane & 15;      // float4 index within the 64-wide row
  int beg = rowptr[w], end = rowptr[w + 1];
  float ax = 0.f, ay = 0.f, az = 0.f, aw = 0.f;
  for (int k = beg + sub; k < end; k += 4) {
    float2 p = cpack[k];
    int   c = __float_as_int(p.x);
    float v = p.y;
    float4 e = ein[(size_t)c * 16 + d4];
    ax = fmaf(v, e.x, ax); ay = fmaf(v, e.y, ay);
    az = fmaf(v, e.z, az); aw = fmaf(v, e.w, aw);
  }
  ax += __shfl_xor(ax, 16); ay += __shfl_xor(ay, 16);
  az += __shfl_xor(az, 16); aw += __shfl_xor(aw, 16);
  ax += __shfl_xor(ax, 32); ay += __shfl_xor(ay, 32);
  az += __shfl_xor(az, 32); aw += __shfl_xor(aw, 32);
  if (sub == 0) eout[(size_t)w * 16 + d4] = make_float4(ax, ay, az, aw);
}

__global__ void k_gather(const float* __restrict__ emb, const int* __restrict__ users,
                         const int* __restrict__ items, float* __restrict__ uacc,
                         float* __restrict__ iacc, int B, int NU, int store) {
  int i = blockIdx.x * blockDim.x + threadIdx.x;
  if (i >= B * D) return;
  int b = i >> 6, d = i & 63;
  float uv = emb[(size_t)users[b] * D + d];
  float iv = emb[(size_t)(NU + items[b]) * D + d];
  if (store) { uacc[i] = uv; iacc[i] = iv; }
  else       { uacc[i] += uv; iacc[i] += iv; }
}

// one wave per (user,item,xij) triple; 72-wide sigmoid/softmax dot
__global__ void k_final(const float* __restrict__ uacc, const float* __restrict__ iacc,
                        const float* __restrict__ xij, const float* __restrict__ xtab,
                        float* __restrict__ out, int B) {
  int w = (blockIdx.x * blockDim.x + threadIdx.x) >> 6;
  int lane = threadIdx.x & 63;
  if (w >= B) return;
  float ue = uacc[w * D + lane] * 0.25f;   // /(L+1)
  float ie = iacc[w * D + lane] * 0.25f;
  float xs = xij[w] - 0.3f;
  float xe = (lane < 8) ? xtab[lane] * xs : 0.f;

  float m = (lane < 8) ? fmaxf(ie, xe) : ie;
  for (int off = 32; off; off >>= 1) m = fmaxf(m, __shfl_xor(m, off));
  float e1 = expf(ie - m);
  float e2 = (lane < 8) ? expf(xe - m) : 0.f;
  float s = e1 + e2;
  for (int off = 32; off; off >>= 1) s += __shfl_xor(s, off);
  float inv = 1.f / s;

  float sig1 = 1.f / (1.f + expf(-ue));
  float term = sig1 * e1 * inv;
  if (lane < 8) {
    float sig2 = 1.f / (1.f + expf(-xe));
    term += sig2 * e2 * inv;
  }
  for (int off = 32; off; off >>= 1) term += __shfl_xor(term, off);
  if (lane == 0) out[w] = term;
}

extern "C" void kernel_launch(void* const* d_in, const int* in_sizes, int n_in,
                              void* d_out, int out_size, void* d_ws, size_t ws_size,
                              hipStream_t stream) {
  const int*   users = (const int*)d_in[0];
  const int*   items = (const int*)d_in[1];
  const float* xij   = (const float*)d_in[2];
  const float* utab  = (const float*)d_in[3];
  const float* itab  = (const float*)d_in[4];
  const float* xtab  = (const float*)d_in[5];
  const int*   erow  = (const int*)d_in[6];
  const int*   ecol  = (const int*)d_in[7];
  const float* evalp = (const float*)d_in[8];
  float* out = (float*)d_out;

  int B  = in_sizes[0];
  int NU = in_sizes[3] / D;
  int NI = in_sizes[4] / D;
  int N  = NU + NI;
  int E  = in_sizes[6];

  char* ws = (char*)d_ws;
  size_t off = 0;
  auto carve = [&](size_t bytes) {
    void* p = ws + off;
    off += (bytes + 255) & ~(size_t)255;
    return p;
  };
  float*  embA   = (float*)carve((size_t)N * D * 4);
  float*  embB   = (float*)carve((size_t)N * D * 4);
  int*    rowptr = (int*)carve((size_t)(N + 1) * 4);
  int*    cnt    = (int*)carve((size_t)N * 4);
  int*    bsum   = (int*)carve(((size_t)(N + 1023) / 1024) * 4);
  float2* cpack  = (float2*)carve((size_t)E * 8);
  float*  uacc   = (float*)carve((size_t)B * D * 4);
  float*  iacc   = (float*)carve((size_t)B * D * 4);
  (void)ws_size; (void)n_in; (void)out_size;

  int nb = (N + 1023) / 1024;

  // --- CSR build ---
  hipLaunchKernelGGL(k_zero, dim3((N + 255) / 256), dim3(256), 0, stream, cnt, N);
  hipLaunchKernelGGL(k_hist, dim3((E + 255) / 256), dim3(256), 0, stream, erow, cnt, E);
  hipLaunchKernelGGL(k_scan1, dim3(nb), dim3(256), 0, stream, cnt, rowptr, bsum, N);
  hipLaunchKernelGGL(k_scan2, dim3(1), dim3(256), 0, stream, bsum, nb);
  hipLaunchKernelGGL(k_scan3, dim3((N + 255) / 256), dim3(256), 0, stream,
                     rowptr, bsum, N, E);
  hipLaunchKernelGGL(k_scatter, dim3((E + 255) / 256), dim3(256), 0, stream,
                     erow, ecol, evalp, rowptr, cnt, cpack, E);

  // --- emb0 = concat(user_table, item_table) ---
  int tot4 = N * D / 4, nu4 = NU * D / 4;
  hipLaunchKernelGGL(k_init_emb, dim3((tot4 + 255) / 256), dim3(256), 0, stream,
                     (const float4*)utab, (const float4*)itab, (float4*)embA, nu4, tot4);

  // hop-0 gather (store), then 3 propagate+gather-add hops
  int gthreads = B * D;
  hipLaunchKernelGGL(k_gather, dim3((gthreads + 255) / 256), dim3(256), 0, stream,
                     embA, users, items, uacc, iacc, B, NU, 1);

  float* ein = embA; float* eout = embB;
  for (int l = 0; l < 3; ++l) {
    hipLaunchKernelGGL(k_prop, dim3((N * 64 + 255) / 256), dim3(256), 0, stream,
                       (const float4*)ein, (float4*)eout, rowptr, cpack, N);
    hipLaunchKernelGGL(k_gather, dim3((gthreads + 255) / 256), dim3(256), 0, stream,
                       eout, users, items, uacc, iacc, B, NU, 0);
    float* t = ein; ein = eout; eout = t;
  }

  hipLaunchKernelGGL(k_final, dim3((B * 64 + 255) / 256), dim3(256), 0, stream,
                     uacc, iacc, xij, xtab, out, B);
}

// Round 7
// 359.199 us; speedup vs baseline: 2.4055x; 1.2201x over previous
//
#include <hip/hip_runtime.h>
#include <math.h>

#define D 64

__global__ void k_zero(int* __restrict__ a, int n) {
  int i = blockIdx.x * blockDim.x + threadIdx.x;
  if (i < n) a[i] = 0;
}

__global__ void k_hist(const int* __restrict__ row, int* __restrict__ cnt, int E) {
  int e = blockIdx.x * blockDim.x + threadIdx.x;
  if (e < E) atomicAdd(&cnt[row[e]], 1);
}

// ---- parallel exclusive scan: cnt[0..N) -> rowptr[0..N] ----
__global__ void k_scan1(const int* __restrict__ cnt, int* __restrict__ rowptr,
                        int* __restrict__ bsum, int N) {
  __shared__ int sh[256];
  int t = threadIdx.x;
  int base = blockIdx.x * 1024 + t * 4;
  int v0 = 0, v1 = 0, v2 = 0, v3 = 0;
  if (base + 3 < N) {
    int4 q = *(const int4*)&cnt[base];
    v0 = q.x; v1 = q.y; v2 = q.z; v3 = q.w;
  } else {
    if (base + 0 < N) v0 = cnt[base + 0];
    if (base + 1 < N) v1 = cnt[base + 1];
    if (base + 2 < N) v2 = cnt[base + 2];
    if (base + 3 < N) v3 = cnt[base + 3];
  }
  int s = v0 + v1 + v2 + v3;
  sh[t] = s;
  __syncthreads();
  for (int off = 1; off < 256; off <<= 1) {
    int x = (t >= off) ? sh[t - off] : 0;
    __syncthreads();
    sh[t] += x;
    __syncthreads();
  }
  int excl = sh[t] - s;
  if (t == 255) bsum[blockIdx.x] = sh[255];
  int p0 = excl, p1 = p0 + v0, p2 = p1 + v1, p3 = p2 + v2;
  if (base + 3 < N) {
    *(int4*)&rowptr[base] = make_int4(p0, p1, p2, p3);
  } else {
    if (base + 0 < N) rowptr[base + 0] = p0;
    if (base + 1 < N) rowptr[base + 1] = p1;
    if (base + 2 < N) rowptr[base + 2] = p2;
    if (base + 3 < N) rowptr[base + 3] = p3;
  }
}

__global__ void k_scan2(int* __restrict__ a, int nb) {
  __shared__ int sums[256];
  int t = threadIdx.x;
  int chunk = (nb + 255) >> 8;
  int lo = t * chunk; if (lo > nb) lo = nb;
  int hi = lo + chunk; if (hi > nb) hi = nb;
  int s = 0;
  for (int i = lo; i < hi; ++i) s += a[i];
  sums[t] = s;
  __syncthreads();
  for (int off = 1; off < 256; off <<= 1) {
    int v = (t >= off) ? sums[t - off] : 0;
    __syncthreads();
    sums[t] += v;
    __syncthreads();
  }
  int run = (t == 0) ? 0 : sums[t - 1];
  for (int i = lo; i < hi; ++i) { int v = a[i]; a[i] = run; run += v; }
}

__global__ void k_scan3(int* __restrict__ rowptr, const int* __restrict__ boff,
                        int N, int E) {
  int i = blockIdx.x * blockDim.x + threadIdx.x;
  if (i < N) rowptr[i] += boff[i >> 10];
  if (i == 0) rowptr[N] = E;
}

// batched scatter: 8 edges/thread, phase-split loads -> atomics -> stores (ILP)
#define SB 8
__global__ void k_scatter(const int* __restrict__ row, const int* __restrict__ col,
                          const float* __restrict__ val, const int* __restrict__ rowptr,
                          int* __restrict__ cnt, float2* __restrict__ cpack, int E) {
  int tid = blockIdx.x * blockDim.x + threadIdx.x;
  int stride = gridDim.x * blockDim.x;
  int r[SB], c[SB], rp[SB], slot[SB];
  float v[SB];
  #pragma unroll
  for (int j = 0; j < SB; ++j) {
    int e = tid + j * stride;
    if (e < E) { r[j] = row[e]; c[j] = col[e]; v[j] = val[e]; }
    else r[j] = -1;
  }
  #pragma unroll
  for (int j = 0; j < SB; ++j) if (r[j] >= 0) rp[j] = rowptr[r[j]];
  #pragma unroll
  for (int j = 0; j < SB; ++j) if (r[j] >= 0) slot[j] = atomicSub(&cnt[r[j]], 1) - 1;
  #pragma unroll
  for (int j = 0; j < SB; ++j)
    if (r[j] >= 0) cpack[rp[j] + slot[j]] = make_float2(__int_as_float(c[j]), v[j]);
}

// one wave per row; lanes = 4 edge-slots x 16 float4-lanes; no atomics.
// hop-1 variant reads emb0 directly from the two tables (no concat copy).
__global__ void k_prop_first(const float4* __restrict__ ut, const float4* __restrict__ it,
                             float4* __restrict__ eout, const int* __restrict__ rowptr,
                             const float2* __restrict__ cpack, int N, int NU) {
  int w = (blockIdx.x * blockDim.x + threadIdx.x) >> 6;
  int lane = threadIdx.x & 63;
  if (w >= N) return;
  int sub = lane >> 4;
  int d4  = lane & 15;
  int beg = rowptr[w], end = rowptr[w + 1];
  float ax = 0.f, ay = 0.f, az = 0.f, aw = 0.f;
  for (int k = beg + sub; k < end; k += 4) {
    float2 p = cpack[k];
    int   c = __float_as_int(p.x);
    float vv = p.y;
    const float4* src = (c < NU) ? (ut + (size_t)c * 16) : (it + (size_t)(c - NU) * 16);
    float4 e = src[d4];
    ax = fmaf(vv, e.x, ax); ay = fmaf(vv, e.y, ay);
    az = fmaf(vv, e.z, az); aw = fmaf(vv, e.w, aw);
  }
  ax += __shfl_xor(ax, 16); ay += __shfl_xor(ay, 16);
  az += __shfl_xor(az, 16); aw += __shfl_xor(aw, 16);
  ax += __shfl_xor(ax, 32); ay += __shfl_xor(ay, 32);
  az += __shfl_xor(az, 32); aw += __shfl_xor(aw, 32);
  if (sub == 0) eout[(size_t)w * 16 + d4] = make_float4(ax, ay, az, aw);
}

__global__ void k_prop(const float4* __restrict__ ein, float4* __restrict__ eout,
                       const int* __restrict__ rowptr, const float2* __restrict__ cpack,
                       int N) {
  int w = (blockIdx.x * blockDim.x + threadIdx.x) >> 6;
  int lane = threadIdx.x & 63;
  if (w >= N) return;
  int sub = lane >> 4;
  int d4  = lane & 15;
  int beg = rowptr[w], end = rowptr[w + 1];
  float ax = 0.f, ay = 0.f, az = 0.f, aw = 0.f;
  for (int k = beg + sub; k < end; k += 4) {
    float2 p = cpack[k];
    int   c = __float_as_int(p.x);
    float vv = p.y;
    float4 e = ein[(size_t)c * 16 + d4];
    ax = fmaf(vv, e.x, ax); ay = fmaf(vv, e.y, ay);
    az = fmaf(vv, e.z, az); aw = fmaf(vv, e.w, aw);
  }
  ax += __shfl_xor(ax, 16); ay += __shfl_xor(ay, 16);
  az += __shfl_xor(az, 16); aw += __shfl_xor(aw, 16);
  ax += __shfl_xor(ax, 32); ay += __shfl_xor(ay, 32);
  az += __shfl_xor(az, 32); aw += __shfl_xor(aw, 32);
  if (sub == 0) eout[(size_t)w * 16 + d4] = make_float4(ax, ay, az, aw);
}

// fused: hop-0/1/2 gathers + on-the-fly hop-3 rows + sigmoid/softmax dot.
// one wave per batch element, lane = dim.
__global__ void k_final(const float* __restrict__ ut, const float* __restrict__ it,
                        const float* __restrict__ emb1, const float* __restrict__ emb2,
                        const int* __restrict__ rowptr, const float2* __restrict__ cpack,
                        const int* __restrict__ users, const int* __restrict__ items,
                        const float* __restrict__ xij, const float* __restrict__ xtab,
                        float* __restrict__ out, int B, int NU) {
  int w = (blockIdx.x * blockDim.x + threadIdx.x) >> 6;
  int lane = threadIdx.x & 63;
  if (w >= B) return;
  int u = users[w];
  int v = NU + items[w];

  float accu = ut[(size_t)u * D + lane] + emb1[(size_t)u * D + lane]
             + emb2[(size_t)u * D + lane];
  {
    int beg = rowptr[u], end = rowptr[u + 1];
    for (int k = beg; k < end; ++k) {
      float2 p = cpack[k];
      int c = __float_as_int(p.x);
      accu = fmaf(p.y, emb2[(size_t)c * D + lane], accu);
    }
  }
  float accv = it[(size_t)(v - NU) * D + lane] + emb1[(size_t)v * D + lane]
             + emb2[(size_t)v * D + lane];
  {
    int beg = rowptr[v], end = rowptr[v + 1];
    for (int k = beg; k < end; ++k) {
      float2 p = cpack[k];
      int c = __float_as_int(p.x);
      accv = fmaf(p.y, emb2[(size_t)c * D + lane], accv);
    }
  }

  float ue = accu * 0.25f;   // /(L+1)
  float ie = accv * 0.25f;
  float xs = xij[w] - 0.3f;
  float xe = (lane < 8) ? xtab[lane] * xs : 0.f;

  float m = (lane < 8) ? fmaxf(ie, xe) : ie;
  for (int off = 32; off; off >>= 1) m = fmaxf(m, __shfl_xor(m, off));
  float e1 = expf(ie - m);
  float e2 = (lane < 8) ? expf(xe - m) : 0.f;
  float s = e1 + e2;
  for (int off = 32; off; off >>= 1) s += __shfl_xor(s, off);
  float inv = 1.f / s;

  float sig1 = 1.f / (1.f + expf(-ue));
  float term = sig1 * e1 * inv;
  if (lane < 8) {
    float sig2 = 1.f / (1.f + expf(-xe));
    term += sig2 * e2 * inv;
  }
  for (int off = 32; off; off >>= 1) term += __shfl_xor(term, off);
  if (lane == 0) out[w] = term;
}

extern "C" void kernel_launch(void* const* d_in, const int* in_sizes, int n_in,
                              void* d_out, int out_size, void* d_ws, size_t ws_size,
                              hipStream_t stream) {
  const int*   users = (const int*)d_in[0];
  const int*   items = (const int*)d_in[1];
  const float* xij   = (const float*)d_in[2];
  const float* utab  = (const float*)d_in[3];
  const float* itab  = (const float*)d_in[4];
  const float* xtab  = (const float*)d_in[5];
  const int*   erow  = (const int*)d_in[6];
  const int*   ecol  = (const int*)d_in[7];
  const float* evalp = (const float*)d_in[8];
  float* out = (float*)d_out;

  int B  = in_sizes[0];
  int NU = in_sizes[3] / D;
  int NI = in_sizes[4] / D;
  int N  = NU + NI;
  int E  = in_sizes[6];

  char* ws = (char*)d_ws;
  size_t off = 0;
  auto carve = [&](size_t bytes) {
    void* p = ws + off;
    off += (bytes + 255) & ~(size_t)255;
    return p;
  };
  float*  emb1   = (float*)carve((size_t)N * D * 4);
  float*  emb2   = (float*)carve((size_t)N * D * 4);
  int*    rowptr = (int*)carve((size_t)(N + 1) * 4);
  int*    cnt    = (int*)carve((size_t)N * 4);
  int*    bsum   = (int*)carve(((size_t)(N + 1023) / 1024) * 4);
  float2* cpack  = (float2*)carve((size_t)E * 8);
  (void)ws_size; (void)n_in; (void)out_size;

  int nb = (N + 1023) / 1024;

  // --- CSR build ---
  hipLaunchKernelGGL(k_zero, dim3((N + 255) / 256), dim3(256), 0, stream, cnt, N);
  hipLaunchKernelGGL(k_hist, dim3((E + 255) / 256), dim3(256), 0, stream, erow, cnt, E);
  hipLaunchKernelGGL(k_scan1, dim3(nb), dim3(256), 0, stream, cnt, rowptr, bsum, N);
  hipLaunchKernelGGL(k_scan2, dim3(1), dim3(256), 0, stream, bsum, nb);
  hipLaunchKernelGGL(k_scan3, dim3((N + 255) / 256), dim3(256), 0, stream,
                     rowptr, bsum, N, E);
  int sblocks = (E + 256 * SB - 1) / (256 * SB);
  hipLaunchKernelGGL(k_scatter, dim3(sblocks), dim3(256), 0, stream,
                     erow, ecol, evalp, rowptr, cnt, cpack, E);

  // --- hops 1,2 full; hop 3 fused into final ---
  hipLaunchKernelGGL(k_prop_first, dim3((N * 64 + 255) / 256), dim3(256), 0, stream,
                     (const float4*)utab, (const float4*)itab, (float4*)emb1,
                     rowptr, cpack, N, NU);
  hipLaunchKernelGGL(k_prop, dim3((N * 64 + 255) / 256), dim3(256), 0, stream,
                     (const float4*)emb1, (float4*)emb2, rowptr, cpack, N);

  hipLaunchKernelGGL(k_final, dim3((B * 64 + 255) / 256), dim3(256), 0, stream,
                     utab, itab, emb1, emb2, rowptr, cpack,
                     users, items, xij, xtab, out, B, NU);
}